// Round 3
// baseline (16704.062 us; speedup 1.0000x reference)
//
#include <hip/hip_runtime.h>

#define T_STEPS 4096
#define IDIM 2048
#define HDIM 2048
#define G4DIM 8192
#define POISON 0xAAAAAAAAu

typedef __attribute__((ext_vector_type(8))) short short8;
typedef __attribute__((ext_vector_type(4))) float f32x4;
typedef __attribute__((ext_vector_type(2))) float f32x2;

__device__ __forceinline__ unsigned short f2bf(float f) {
  unsigned int u = __float_as_uint(f);
  u += 0x7fffu + ((u >> 16) & 1u);
  return (unsigned short)(u >> 16);
}
__device__ __forceinline__ float bf2f(unsigned short h) {
  return __uint_as_float(((unsigned int)h) << 16);
}

// C[M,N] = act( sum_k A[m,k]*B[n,k] + bias[n] ), split-bf16 3-pass MFMA.
template <int ACT_SIGMOID, int OUT_BF16>
__global__ __launch_bounds__(256) void gemm_bt(
    const float* __restrict__ A, const float* __restrict__ B,
    const float* __restrict__ bias, void* __restrict__ Cout,
    int M, int N, int K)
{
  __shared__ short Ah[64][40];
  __shared__ short Al[64][40];
  __shared__ short Bh[64][40];
  __shared__ short Bl[64][40];
  const int tid  = threadIdx.x;
  const int wave = tid >> 6, lane = tid & 63;
  const int bn = blockIdx.x * 64, bm = blockIdx.y * 64;
  const int srow = tid >> 2, sc8 = (tid & 3) * 8;
  const int wm = (wave >> 1) * 32, wn = (wave & 1) * 32;
  const int lq = lane >> 4, lr = lane & 15;
  f32x4 acc[2][2] = {};

  for (int k0 = 0; k0 < K; k0 += 32) {
    __syncthreads();
    {
      const float* src = A + (size_t)(bm + srow) * K + k0 + sc8;
      float4 v0 = *(const float4*)(src);
      float4 v1 = *(const float4*)(src + 4);
      float vv[8] = {v0.x, v0.y, v0.z, v0.w, v1.x, v1.y, v1.z, v1.w};
      short8 vh, vl;
      #pragma unroll
      for (int i = 0; i < 8; ++i) {
        unsigned short hb = f2bf(vv[i]);
        vh[i] = (short)hb;
        vl[i] = (short)f2bf(vv[i] - bf2f(hb));
      }
      *(short8*)&Ah[srow][sc8] = vh;
      *(short8*)&Al[srow][sc8] = vl;
    }
    {
      const float* src = B + (size_t)(bn + srow) * K + k0 + sc8;
      float4 v0 = *(const float4*)(src);
      float4 v1 = *(const float4*)(src + 4);
      float vv[8] = {v0.x, v0.y, v0.z, v0.w, v1.x, v1.y, v1.z, v1.w};
      short8 vh, vl;
      #pragma unroll
      for (int i = 0; i < 8; ++i) {
        unsigned short hb = f2bf(vv[i]);
        vh[i] = (short)hb;
        vl[i] = (short)f2bf(vv[i] - bf2f(hb));
      }
      *(short8*)&Bh[srow][sc8] = vh;
      *(short8*)&Bl[srow][sc8] = vl;
    }
    __syncthreads();

    short8 ah0 = *(const short8*)&Ah[wm +      lr][lq * 8];
    short8 al0 = *(const short8*)&Al[wm +      lr][lq * 8];
    short8 ah1 = *(const short8*)&Ah[wm + 16 + lr][lq * 8];
    short8 al1 = *(const short8*)&Al[wm + 16 + lr][lq * 8];
    short8 bh0 = *(const short8*)&Bh[wn +      lr][lq * 8];
    short8 bl0 = *(const short8*)&Bl[wn +      lr][lq * 8];
    short8 bh1 = *(const short8*)&Bh[wn + 16 + lr][lq * 8];
    short8 bl1 = *(const short8*)&Bl[wn + 16 + lr][lq * 8];

    acc[0][0] = __builtin_amdgcn_mfma_f32_16x16x32_bf16(ah0, bh0, acc[0][0], 0, 0, 0);
    acc[0][0] = __builtin_amdgcn_mfma_f32_16x16x32_bf16(ah0, bl0, acc[0][0], 0, 0, 0);
    acc[0][0] = __builtin_amdgcn_mfma_f32_16x16x32_bf16(al0, bh0, acc[0][0], 0, 0, 0);

    acc[0][1] = __builtin_amdgcn_mfma_f32_16x16x32_bf16(ah0, bh1, acc[0][1], 0, 0, 0);
    acc[0][1] = __builtin_amdgcn_mfma_f32_16x16x32_bf16(ah0, bl1, acc[0][1], 0, 0, 0);
    acc[0][1] = __builtin_amdgcn_mfma_f32_16x16x32_bf16(al0, bh1, acc[0][1], 0, 0, 0);

    acc[1][0] = __builtin_amdgcn_mfma_f32_16x16x32_bf16(ah1, bh0, acc[1][0], 0, 0, 0);
    acc[1][0] = __builtin_amdgcn_mfma_f32_16x16x32_bf16(ah1, bl0, acc[1][0], 0, 0, 0);
    acc[1][0] = __builtin_amdgcn_mfma_f32_16x16x32_bf16(al1, bh0, acc[1][0], 0, 0, 0);

    acc[1][1] = __builtin_amdgcn_mfma_f32_16x16x32_bf16(ah1, bh1, acc[1][1], 0, 0, 0);
    acc[1][1] = __builtin_amdgcn_mfma_f32_16x16x32_bf16(ah1, bl1, acc[1][1], 0, 0, 0);
    acc[1][1] = __builtin_amdgcn_mfma_f32_16x16x32_bf16(al1, bh1, acc[1][1], 0, 0, 0);
  }

  #pragma unroll
  for (int mi = 0; mi < 2; ++mi) {
    #pragma unroll
    for (int ni = 0; ni < 2; ++ni) {
      #pragma unroll
      for (int rr = 0; rr < 4; ++rr) {
        int row = bm + wm + mi * 16 + lq * 4 + rr;
        int col = bn + wn + ni * 16 + lr;
        float v = acc[mi][ni][rr];
        if (bias) v += bias[col];
        if (ACT_SIGMOID) v = 1.f / (1.f + __expf(-v));
        if (OUT_BF16)
          ((unsigned short*)Cout)[(size_t)row * N + col] = f2bf(v);
        else
          ((float*)Cout)[(size_t)row * N + col] = v;
      }
    }
  }
}

// Persistent-weight LSTM scan, v3.
// 256 WGs x 1024 threads (one per CU, all co-resident). WG b owns hidden units
// [b*8, b*8+8). Compute layout = v2 (thread: kc=tid>>3 K-chunk of 16, u=tid&7,
// 4 gate rows, 64 weight VGPRs). Changes vs v2:
//   * Compute waves spin on an LDS flag, not global memory (kills the LLC
//     poll storm that limited v2).
//   * Wave 15 is the fetcher: polls 16 agent-atomic sentinel dwords (sampled
//     producers; all WGs are dataflow-lockstep), then bulk-reads h(t) with
//     plain cacheable dwordx4 (L2-shared across the XCD's 32 WGs). h values
//     are WRITE-ONCE (poison -> final), so a cached non-poison value is always
//     correct; stale-poison dwords are re-read with agent-atomic loads and
//     that address is never needed again.
//   * Wave 0 keeps the finalize; wave 15's sentinel wait overlaps it.
__global__ __launch_bounds__(1024, 4) void lstm_scan(
    const float* __restrict__ Whh,
    const float* __restrict__ b_ih, const float* __restrict__ b_hh,
    const unsigned short* __restrict__ gx,   // [T][8192] bf16
    float* __restrict__ hs)                  // [T][2048] fp32, poisoned 0xAA
{
  const int b    = blockIdx.x;
  const int tid  = threadIdx.x;
  const int u    = tid & 7;
  const int kc   = tid >> 3;
  const int wv   = tid >> 6;
  const int lane = tid & 63;

  f32x2 w2[4][8];
  #pragma unroll
  for (int g = 0; g < 4; ++g) {
    const float* wp = Whh + (size_t)(g * HDIM + b * 8 + u) * HDIM + kc * 16;
    #pragma unroll
    for (int i = 0; i < 4; ++i) {
      float4 v = *(const float4*)(wp + 4 * i);
      w2[g][2 * i]     = f32x2{v.x, v.y};
      w2[g][2 * i + 1] = f32x2{v.z, v.w};
    }
  }
  float bias_r = 0.f;
  if (tid < 32) {
    int br = (tid >> 3) * HDIM + b * 8 + (tid & 7);
    bias_r = b_ih[br] + b_hh[br];
  }
  float cval = 0.f;  // lanes tid<8 only

  // h double-buffer: 128 chunks of 16 dwords, stride 20 -> broadcast reads
  // tile all 32 banks conflict-free.
  __shared__ float hbuf[2][128 * 20];
  __shared__ float partials[2][16][33];
  __shared__ int sh_flag;

  for (int i = tid; i < 128 * 20; i += 1024) hbuf[0][i] = 0.f;
  if (tid == 0) sh_flag = 0;
  __syncthreads();

  unsigned int* hs_u = (unsigned int*)hs;

  for (int t = 0; t < T_STEPS; ++t) {
    // gx for this step (independent of h -> issue before the spin)
    float gxv = 0.f;
    if (tid < 32)
      gxv = bf2f(gx[(size_t)t * G4DIM + (tid >> 3) * HDIM + b * 8 + (tid & 7)]);

    // wait for h(t-1) broadcast into LDS (wave 15 exits immediately: it set it)
    while (__hip_atomic_load(&sh_flag, __ATOMIC_ACQUIRE,
                             __HIP_MEMORY_SCOPE_WORKGROUP) < t)
      __builtin_amdgcn_s_sleep(1);

    const float* hb = hbuf[t & 1];
    f32x2 acc0{0.f, 0.f}, acc1{0.f, 0.f}, acc2{0.f, 0.f}, acc3{0.f, 0.f};
    #pragma unroll
    for (int i = 0; i < 4; ++i) {
      float4 hv = *(const float4*)&hb[kc * 20 + i * 4];
      f32x2 ha{hv.x, hv.y}, hc{hv.z, hv.w};
      acc0 += w2[0][2 * i] * ha;  acc0 += w2[0][2 * i + 1] * hc;
      acc1 += w2[1][2 * i] * ha;  acc1 += w2[1][2 * i + 1] * hc;
      acc2 += w2[2][2 * i] * ha;  acc2 += w2[2][2 * i + 1] * hc;
      acc3 += w2[3][2 * i] * ha;  acc3 += w2[3][2 * i + 1] * hc;
    }
    float s0 = acc0[0] + acc0[1];
    float s1 = acc1[0] + acc1[1];
    float s2 = acc2[0] + acc2[1];
    float s3 = acc3[0] + acc3[1];
    #pragma unroll
    for (int m = 8; m <= 32; m <<= 1) {
      s0 += __shfl_xor(s0, m, 64);
      s1 += __shfl_xor(s1, m, 64);
      s2 += __shfl_xor(s2, m, 64);
      s3 += __shfl_xor(s3, m, 64);
    }
    if ((tid & 56) == 0) {  // first 8 lanes of each wave
      partials[t & 1][wv][0 * 8 + u] = s0;
      partials[t & 1][wv][1 * 8 + u] = s1;
      partials[t & 1][wv][2 * 8 + u] = s2;
      partials[t & 1][wv][3 * 8 + u] = s3;
    }
    __syncthreads();

    if (wv == 0) {  // finalize: c,h update + global h store
      float gval = 0.f;
      if (tid < 32) {
        float s = gxv + bias_r;
        #pragma unroll
        for (int q = 0; q < 16; ++q) s += partials[t & 1][q][tid];
        gval = s;
      }
      float g_i = __shfl(gval, tid);
      float g_f = __shfl(gval, tid + 8);
      float g_g = __shfl(gval, tid + 16);
      float g_o = __shfl(gval, tid + 24);
      if (tid < 8) {
        float is = 1.f / (1.f + __expf(-g_i));
        float fs = 1.f / (1.f + __expf(-g_f));
        float os = 1.f / (1.f + __expf(-g_o));
        float e2 = __expf(-2.f * fabsf(g_g));
        float tg = (1.f - e2) / (1.f + e2);
        tg = (g_g < 0.f) ? -tg : tg;
        float cn = fs * cval + is * tg;
        cval = cn;
        float ec = __expf(-2.f * fabsf(cn));
        float tc = (1.f - ec) / (1.f + ec);
        tc = (cn < 0.f) ? -tc : tc;
        float hn = os * tc;
        __hip_atomic_store(hs_u + (size_t)t * HDIM + b * 8 + tid,
                           __float_as_uint(hn),
                           __ATOMIC_RELAXED, __HIP_MEMORY_SCOPE_AGENT);
      }
    } else if (wv == 15 && t + 1 < T_STEPS) {  // fetcher
      const unsigned int* src = hs_u + (size_t)t * HDIM;
      // phase 1: sentinels — 16 sampled producers (WGs 15,31,...,255)
      if (lane < 16) {
        const unsigned int* sp = src + lane * 128 + 127;
        while (__hip_atomic_load(sp, __ATOMIC_RELAXED,
                                 __HIP_MEMORY_SCOPE_AGENT) == POISON)
          __builtin_amdgcn_s_sleep(2);
      }
      // phase 2: bulk cacheable read — lane owns dwords [lane*32, lane*32+32)
      uint4 gv[8];
      const uint4* s4 = (const uint4*)(src + lane * 32);
      #pragma unroll
      for (int g = 0; g < 8; ++g) gv[g] = s4[g];
      // phase 3: fix stale-poison groups with agent-atomic re-reads
      for (;;) {
        unsigned pend = 0;
        #pragma unroll
        for (int g = 0; g < 8; ++g)
          if (gv[g].x == POISON || gv[g].y == POISON ||
              gv[g].z == POISON || gv[g].w == POISON) pend |= 1u << g;
        if (__ballot(pend != 0) == 0ull) break;
        #pragma unroll
        for (int g = 0; g < 8; ++g) {
          if (pend & (1u << g)) {
            const unsigned int* q = src + lane * 32 + g * 4;
            gv[g].x = __hip_atomic_load(q + 0, __ATOMIC_RELAXED, __HIP_MEMORY_SCOPE_AGENT);
            gv[g].y = __hip_atomic_load(q + 1, __ATOMIC_RELAXED, __HIP_MEMORY_SCOPE_AGENT);
            gv[g].z = __hip_atomic_load(q + 2, __ATOMIC_RELAXED, __HIP_MEMORY_SCOPE_AGENT);
            gv[g].w = __hip_atomic_load(q + 3, __ATOMIC_RELAXED, __HIP_MEMORY_SCOPE_AGENT);
          }
        }
        __builtin_amdgcn_s_sleep(1);
      }
      // scatter into padded LDS layout: dword d = lane*32+g*4+j ->
      // chunk 2*lane+(g>>2), offset (g&3)*4
      float* dst = hbuf[(t + 1) & 1];
      #pragma unroll
      for (int g = 0; g < 8; ++g) {
        float4 w4;
        w4.x = __uint_as_float(gv[g].x); w4.y = __uint_as_float(gv[g].y);
        w4.z = __uint_as_float(gv[g].z); w4.w = __uint_as_float(gv[g].w);
        *(float4*)&dst[(2 * lane + (g >> 2)) * 20 + (g & 3) * 4] = w4;
      }
      __threadfence_block();
      if (lane == 0)
        __hip_atomic_store(&sh_flag, t + 1, __ATOMIC_RELEASE,
                           __HIP_MEMORY_SCOPE_WORKGROUP);
    }
    // no trailing barrier: partials double-buffered; writes to partials[t&1]
    // recur at t+2, which is gated by flag>=t+2 -> wave15 fetched h(t+1) ->
    // all wave0s finished finalize(t) (they produced h(t+1) after it) and all
    // waves passed barrier(t+1).
  }
}

extern "C" void kernel_launch(void* const* d_in, const int* in_sizes, int n_in,
                              void* d_out, int out_size, void* d_ws, size_t ws_size,
                              hipStream_t stream) {
  (void)in_sizes; (void)n_in; (void)out_size; (void)ws_size;
  const float* x    = (const float*)d_in[0];   // [1,4096,2048]
  const float* W_ih = (const float*)d_in[1];   // [8192,2048]
  const float* W_hh = (const float*)d_in[2];   // [8192,2048]
  const float* b_ih = (const float*)d_in[3];   // [8192]
  const float* b_hh = (const float*)d_in[4];   // [8192]
  const float* Wo   = (const float*)d_in[5];   // [2048,2048]
  const float* bo   = (const float*)d_in[6];   // [2048]
  float* out = (float*)d_out;

  char* ws = (char*)d_ws;
  unsigned short* gx = (unsigned short*)ws;               // 64 MiB bf16
  float* hs = (float*)(ws + (size_t)T_STEPS * G4DIM * 2); // 32 MiB fp32

  // our own in-graph poison: the scan's dataflow sync depends on it
  hipMemsetAsync(hs, 0xAA, (size_t)T_STEPS * HDIM * sizeof(float), stream);

  // gx = x @ W_ih^T  (biases folded into the scan)
  gemm_bt<0, 1><<<dim3(G4DIM / 64, T_STEPS / 64), 256, 0, stream>>>(
      x, W_ih, nullptr, gx, T_STEPS, G4DIM, IDIM);

  lstm_scan<<<256, 1024, 0, stream>>>(W_hh, b_ih, b_hh, gx, hs);

  // out = sigmoid(hs @ Wo^T + bo)
  gemm_bt<1, 0><<<dim3(IDIM / 64, T_STEPS / 64), 256, 0, stream>>>(
      hs, Wo, bo, out, T_STEPS, IDIM, HDIM);
}